// Round 1
// 281.463 us; speedup vs baseline: 1.0480x; 1.0480x over previous
//
#include <hip/hip_runtime.h>

typedef unsigned short ushort_t;
typedef __attribute__((ext_vector_type(8))) short short8;
typedef __attribute__((ext_vector_type(4))) float floatx4;

__device__ __forceinline__ unsigned short f2bf(float f) {
  unsigned int u = __float_as_uint(f);
  u += 0x7fffu + ((u >> 16) & 1u);
  return (unsigned short)(u >> 16);
}

// packed f32x2 -> bf16x2 (RNE), single VALU op
__device__ __forceinline__ unsigned int cvt_pk_bf16(float a, float b) {
  unsigned int r;
  asm("v_cvt_pk_bf16_f32 %0, %1, %2" : "=v"(r) : "v"(a), "v"(b));
  return r;
}

__device__ __forceinline__ void gl_lds16(const void* g, void* l) {
  __builtin_amdgcn_global_load_lds((const __attribute__((address_space(1))) void*)g,
                                   (__attribute__((address_space(3))) void*)l,
                                   16, 0, 0);
}

// ---------------- prep kernels ----------------

__global__ void conv_x_kernel(const float* __restrict__ src, ushort_t* __restrict__ dst, int n4) {
  int i = blockIdx.x * blockDim.x + threadIdx.x;
  if (i >= n4) return;
  float4 v = ((const float4*)src)[i];
  union { ushort_t u[4]; unsigned long long ll; } o;
  o.u[0] = f2bf(v.x); o.u[1] = f2bf(v.y); o.u[2] = f2bf(v.z); o.u[3] = f2bf(v.w);
  ((unsigned long long*)dst)[i] = o.ll;
}

// src fp32 [R][C] row-major  ->  dst bf16 [C][R] row-major (row stride R)
__global__ void transpose_conv(const float* __restrict__ src, ushort_t* __restrict__ dst,
                               int R, int C) {
  __shared__ float tile[32][33];
  int c0 = blockIdx.x * 32, r0 = blockIdx.y * 32;
  int tx = threadIdx.x, ty = threadIdx.y;
#pragma unroll
  for (int i = ty; i < 32; i += 8)
    tile[i][tx] = src[(long)(r0 + i) * C + c0 + tx];
  __syncthreads();
#pragma unroll
  for (int i = ty; i < 32; i += 8)
    dst[(long)(c0 + i) * R + r0 + tx] = f2bf(tile[tx][i]);
}

// ---------------- GEMM: C[M,N] = A[M,K] * B^T (B stored [N][K]), bf16 in, fp32 acc ----------------
// EPI=0: QKV epilogue (N=3072): n<2048 -> q_buf [32][2048][64] (scaled 0.125*log2e for exp2-domain
//        softmax), n<2560 -> k_buf [8][2048][64], else v^T buf [8][64][2048]
// EPI=1: fp32 C output
template <int EPI>
__global__ __launch_bounds__(256, 2) void gemm_bt(
    const ushort_t* __restrict__ A, const ushort_t* __restrict__ B,
    float* __restrict__ C,
    ushort_t* __restrict__ qb, ushort_t* __restrict__ kb, ushort_t* __restrict__ vb,
    int M, int N, int K) {
  __shared__ ushort_t As[128 * 32];
  __shared__ ushort_t Bs[128 * 32];
  const int t = threadIdx.x;
  const int w = t >> 6, lane = t & 63;
  const int m = lane & 15, quad = lane >> 4;
  const int m0 = blockIdx.y * 128, n0 = blockIdx.x * 128;
  const int wr = w >> 1, wc = w & 1;

  floatx4 acc[4][4] = {};

  for (int kk = 0; kk < K; kk += 32) {
    __syncthreads();
#pragma unroll
    for (int i = 0; i < 2; ++i) {
      int c = i * 256 + t;
      int c0 = i * 256 + w * 64;
      gl_lds16(A + (long)(m0 + (c >> 2)) * K + kk + (c & 3) * 8, As + c0 * 8);
      gl_lds16(B + (long)(n0 + (c >> 2)) * K + kk + (c & 3) * 8, Bs + c0 * 8);
    }
    __syncthreads();
    short8 af[4], bf[4];
#pragma unroll
    for (int i = 0; i < 4; ++i)
      af[i] = *(const short8*)(As + (wr * 64 + i * 16 + m) * 32 + quad * 8);
#pragma unroll
    for (int j = 0; j < 4; ++j)
      bf[j] = *(const short8*)(Bs + (wc * 64 + j * 16 + m) * 32 + quad * 8);
#pragma unroll
    for (int i = 0; i < 4; ++i)
#pragma unroll
      for (int j = 0; j < 4; ++j)
        acc[i][j] = __builtin_amdgcn_mfma_f32_16x16x32_bf16(af[i], bf[j], acc[i][j], 0, 0, 0);
  }

#pragma unroll
  for (int i = 0; i < 4; ++i)
#pragma unroll
    for (int j = 0; j < 4; ++j)
#pragma unroll
      for (int r = 0; r < 4; ++r) {
        float v = acc[i][j][r];
        int row = m0 + wr * 64 + i * 16 + quad * 4 + r;
        int col = n0 + wc * 64 + j * 16 + m;
        if (EPI == 1) {
          C[(long)row * N + col] = v;
        } else {
          if (col < 2048) {
            // 0.125 * log2(e): softmax runs in exp2 domain
            qb[((((col >> 6) * 2048) + row) << 6) | (col & 63)] = f2bf(v * 0.18033688f);
          } else if (col < 2560) {
            int g = (col - 2048) >> 6;
            kb[(((g * 2048) + row) << 6) | (col & 63)] = f2bf(v);
          } else {
            int g = (col - 2560) >> 6;
            vb[(long)((g << 6) | (col & 63)) * 2048 + row] = f2bf(v);
          }
        }
      }
}

// ---------------- flash attention ----------------
// Q [32][S][64] bf16 (pre-scaled by 0.125*log2e), K [8][S][64] bf16, V^T [8][64][S] bf16
// -> O [S][2048] bf16
//
// Swapped QK^T: sacc = mfma(K_frag, Q_frag) so D[k][q]: each lane holds P-row slices for
// q = lane&15 -> softmax max/sum are in-lane trees + 2 cross-quad shuffles, and P is
// k-contiguous per lane -> packed b64 LDS writes.
//
// LDS swizzles (all reads/writes verified conflict-free at 32-bank minimum):
//   Ks/Vs: 64B rows, 16B slot ^= (row>>1)&3; applied to global SOURCE of global_load_lds
//          (dest must stay linear), and to the ds_read address.
//   Ps:    128B rows, byte ^= (row&7)<<4 on both write and read.
__global__ __launch_bounds__(256, 2) void flash_kernel(
    const ushort_t* __restrict__ Q, const ushort_t* __restrict__ Kb,
    const ushort_t* __restrict__ Vb, ushort_t* __restrict__ O, int S) {
  __shared__ __attribute__((aligned(16))) ushort_t Ks[2 * 128 * 32];  // 16KB [kq][krow][32]
  __shared__ __attribute__((aligned(16))) ushort_t Vs[4 * 64 * 32];   // 16KB [kt][d][32]
  __shared__ __attribute__((aligned(16))) ushort_t Ps[4 * 32 * 64];   // 16KB per-wave [32 q][64 k-half]
  const int t = threadIdx.x;
  const int w = t >> 6, lane = t & 63;
  const int m = lane & 15, quad = lane >> 4;
  const int h = blockIdx.y, g = h >> 2;
  const int q0 = blockIdx.x * 128;
  const ushort_t* qp = Q + (long)h * S * 64;
  const ushort_t* kp = Kb + (long)g * S * 64;
  const ushort_t* vp = Vb + (long)g * 64 * S;

  short8 qf[2][2];
#pragma unroll
  for (int rt = 0; rt < 2; ++rt)
#pragma unroll
    for (int kq = 0; kq < 2; ++kq)
      qf[rt][kq] = *(const short8*)(qp + (long)(q0 + w * 32 + rt * 16 + m) * 64 + kq * 32 + quad * 8);

  float mcur[2] = {-1e30f, -1e30f};
  float lcur[2] = {0.f, 0.f};
  floatx4 oacc[2][4] = {};
  char* PwB = (char*)Ps + w * 4096;
  const int swz = (m & 7) << 4;                    // Ps swizzle key (row&7 == m&7 here)
  const int kvswz = (quad ^ ((m >> 1) & 3)) * 8;   // Ks/Vs read slot (ushort units)

  for (int t0 = 0; t0 < S; t0 += 128) {
    __syncthreads();
#pragma unroll
    for (int i = 0; i < 4; ++i) {
      int c = i * 256 + t;
      int c0 = i * 256 + w * 64;
      int sl = ((c & 3) ^ ((c >> 3) & 3)) * 8;  // pre-swizzled global slot; LDS dest linear
      gl_lds16(kp + (long)(t0 + ((c >> 2) & 127)) * 64 + (c >> 9) * 32 + sl, Ks + c0 * 8);
      gl_lds16(vp + (long)((c >> 2) & 63) * S + t0 + (c >> 8) * 32 + sl, Vs + c0 * 8);
    }
    __syncthreads();

    // ---- QK^T (swapped: rows = k, cols = q) ----
    floatx4 sacc[2][8] = {};
    __builtin_amdgcn_s_setprio(1);
#pragma unroll
    for (int ct = 0; ct < 8; ++ct) {
      short8 kf0 = *(const short8*)(Ks + (ct * 16 + m) * 32 + kvswz);
      short8 kf1 = *(const short8*)(Ks + 4096 + (ct * 16 + m) * 32 + kvswz);
#pragma unroll
      for (int rt = 0; rt < 2; ++rt) {
        sacc[rt][ct] = __builtin_amdgcn_mfma_f32_16x16x32_bf16(kf0, qf[rt][0], sacc[rt][ct], 0, 0, 0);
        sacc[rt][ct] = __builtin_amdgcn_mfma_f32_16x16x32_bf16(kf1, qf[rt][1], sacc[rt][ct], 0, 0, 0);
      }
    }
    __builtin_amdgcn_s_setprio(0);

    // ---- online softmax, state indexed by q = m ----
    float mnew[2], al[2];
#pragma unroll
    for (int rt = 0; rt < 2; ++rt) {
      float mt[8];
#pragma unroll
      for (int ct = 0; ct < 8; ++ct)
        mt[ct] = fmaxf(fmaxf(sacc[rt][ct][0], sacc[rt][ct][1]),
                       fmaxf(sacc[rt][ct][2], sacc[rt][ct][3]));
      float mx = fmaxf(fmaxf(fmaxf(mt[0], mt[1]), fmaxf(mt[2], mt[3])),
                       fmaxf(fmaxf(mt[4], mt[5]), fmaxf(mt[6], mt[7])));
      mx = fmaxf(mx, __shfl_xor(mx, 16));
      mx = fmaxf(mx, __shfl_xor(mx, 32));
      mnew[rt] = fmaxf(mcur[rt], mx);
      al[rt] = exp2f(mcur[rt] - mnew[rt]);
      mcur[rt] = mnew[rt];
    }

    // rescale O: broadcast col-state al (q=m) to row position q=quad*4+r
#pragma unroll
    for (int rt = 0; rt < 2; ++rt)
#pragma unroll
      for (int r = 0; r < 4; ++r) {
        float alr = __shfl(al[rt], quad * 4 + r);
#pragma unroll
        for (int ct = 0; ct < 4; ++ct) oacc[rt][ct][r] *= alr;
      }

    float ls[2] = {0.f, 0.f};
#pragma unroll
    for (int hh = 0; hh < 2; ++hh) {
      // exp + pack + write k-half of P (rows rt*16+m, 128B rows, XOR-swizzled)
#pragma unroll
      for (int rt = 0; rt < 2; ++rt)
#pragma unroll
        for (int cl = 0; cl < 4; ++cl) {
          int ct = hh * 4 + cl;
          float p0 = exp2f(sacc[rt][ct][0] - mnew[rt]);
          float p1 = exp2f(sacc[rt][ct][1] - mnew[rt]);
          float p2 = exp2f(sacc[rt][ct][2] - mnew[rt]);
          float p3 = exp2f(sacc[rt][ct][3] - mnew[rt]);
          ls[rt] += (p0 + p1) + (p2 + p3);
          uint2 pk;
          pk.x = cvt_pk_bf16(p0, p1);
          pk.y = cvt_pk_bf16(p2, p3);
          *(uint2*)(PwB + ((rt * 2048 + m * 128 + cl * 32 + quad * 8) ^ swz)) = pk;
        }
      // ---- PV over this half ----
      __builtin_amdgcn_s_setprio(1);
#pragma unroll
      for (int ktl = 0; ktl < 2; ++ktl) {
        int kt = hh * 2 + ktl;
        short8 pf[2];
#pragma unroll
        for (int rt = 0; rt < 2; ++rt)
          pf[rt] = *(const short8*)(PwB + ((rt * 2048 + m * 128 + ktl * 64 + quad * 16) ^ swz));
#pragma unroll
        for (int ct = 0; ct < 4; ++ct) {
          short8 vf = *(const short8*)(Vs + kt * 2048 + (ct * 16 + m) * 32 + kvswz);
#pragma unroll
          for (int rt = 0; rt < 2; ++rt)
            oacc[rt][ct] = __builtin_amdgcn_mfma_f32_16x16x32_bf16(pf[rt], vf, oacc[rt][ct], 0, 0, 0);
        }
      }
      __builtin_amdgcn_s_setprio(0);
    }

#pragma unroll
    for (int rt = 0; rt < 2; ++rt) {
      float s_ = ls[rt];
      s_ += __shfl_xor(s_, 16);
      s_ += __shfl_xor(s_, 32);
      lcur[rt] = lcur[rt] * al[rt] + s_;
    }
  }

#pragma unroll
  for (int rt = 0; rt < 2; ++rt) {
    float linv = 1.f / lcur[rt];
#pragma unroll
    for (int r = 0; r < 4; ++r) {
      float lr = __shfl(linv, quad * 4 + r);
      int srow = q0 + w * 32 + rt * 16 + quad * 4 + r;
#pragma unroll
      for (int ct = 0; ct < 4; ++ct)
        O[(long)srow * 2048 + h * 64 + ct * 16 + m] = f2bf(oacc[rt][ct][r] * lr);
    }
  }
}

// ---------------- launch ----------------

extern "C" void kernel_launch(void* const* d_in, const int* in_sizes, int n_in,
                              void* d_out, int out_size, void* d_ws, size_t ws_size,
                              hipStream_t stream) {
  (void)in_sizes; (void)n_in; (void)out_size; (void)ws_size;
  const float* x  = (const float*)d_in[0];
  const float* wq = (const float*)d_in[1];
  const float* wk = (const float*)d_in[2];
  const float* wv = (const float*)d_in[3];
  const float* wo = (const float*)d_in[4];
  float* out = (float*)d_out;
  char* ws = (char*)d_ws;
  const size_t MB = 1u << 20;

  ushort_t* xb    = (ushort_t*)(ws);            // 8 MB  x bf16 [2048][2048]
  ushort_t* wqkvT = (ushort_t*)(ws + 8 * MB);   // 12 MB [3072][2048]
  ushort_t* woT   = (ushort_t*)(ws + 20 * MB);  // 8 MB  [2048][2048]
  ushort_t* qbuf  = (ushort_t*)(ws + 28 * MB);  // 8 MB  [32][2048][64]
  ushort_t* kbuf  = (ushort_t*)(ws + 36 * MB);  // 2 MB  [8][2048][64]
  ushort_t* vbuf  = (ushort_t*)(ws + 38 * MB);  // 2 MB  [8][64][2048]
  ushort_t* attn  = xb;                         // alias: xb dead after gemm<0>

  conv_x_kernel<<<4096, 256, 0, stream>>>(x, xb, 2048 * 2048 / 4);
  dim3 tb(32, 8);
  transpose_conv<<<dim3(64, 64), tb, 0, stream>>>(wq, wqkvT, 2048, 2048);
  transpose_conv<<<dim3(16, 64), tb, 0, stream>>>(wk, wqkvT + 2048 * 2048, 2048, 512);
  transpose_conv<<<dim3(16, 64), tb, 0, stream>>>(wv, wqkvT + 2560 * 2048, 2048, 512);
  transpose_conv<<<dim3(64, 64), tb, 0, stream>>>(wo, woT, 2048, 2048);

  gemm_bt<0><<<dim3(24, 16), 256, 0, stream>>>(xb, wqkvT, nullptr, qbuf, kbuf, vbuf,
                                               2048, 3072, 2048);
  flash_kernel<<<dim3(16, 32), 256, 0, stream>>>(qbuf, kbuf, vbuf, attn, 2048);
  gemm_bt<1><<<dim3(16, 16), 256, 0, stream>>>(attn, woT, out, nullptr, nullptr, nullptr,
                                               2048, 2048, 2048);
}

// Round 3
// 272.636 us; speedup vs baseline: 1.0819x; 1.0324x over previous
//
#include <hip/hip_runtime.h>

typedef unsigned short ushort_t;
typedef __attribute__((ext_vector_type(8))) short short8;
typedef __attribute__((ext_vector_type(4))) float floatx4;

__device__ __forceinline__ unsigned short f2bf(float f) {
  unsigned int u = __float_as_uint(f);
  u += 0x7fffu + ((u >> 16) & 1u);
  return (unsigned short)(u >> 16);
}

// packed f32x2 -> bf16x2 (RNE), single VALU op
__device__ __forceinline__ unsigned int cvt_pk_bf16(float a, float b) {
  unsigned int r;
  asm("v_cvt_pk_bf16_f32 %0, %1, %2" : "=v"(r) : "v"(a), "v"(b));
  return r;
}

__device__ __forceinline__ void gl_lds16(const void* g, void* l) {
  __builtin_amdgcn_global_load_lds((const __attribute__((address_space(1))) void*)g,
                                   (__attribute__((address_space(3))) void*)l,
                                   16, 0, 0);
}

// ---------------- prep kernels ----------------

__global__ void conv_x_kernel(const float* __restrict__ src, ushort_t* __restrict__ dst, int n4) {
  int i = blockIdx.x * blockDim.x + threadIdx.x;
  if (i >= n4) return;
  float4 v = ((const float4*)src)[i];
  union { ushort_t u[4]; unsigned long long ll; } o;
  o.u[0] = f2bf(v.x); o.u[1] = f2bf(v.y); o.u[2] = f2bf(v.z); o.u[3] = f2bf(v.w);
  ((unsigned long long*)dst)[i] = o.ll;
}

// src fp32 [R][C] row-major  ->  dst bf16 [C][R] row-major (row stride R)
__global__ void transpose_conv(const float* __restrict__ src, ushort_t* __restrict__ dst,
                               int R, int C) {
  __shared__ float tile[32][33];
  int c0 = blockIdx.x * 32, r0 = blockIdx.y * 32;
  int tx = threadIdx.x, ty = threadIdx.y;
#pragma unroll
  for (int i = ty; i < 32; i += 8)
    tile[i][tx] = src[(long)(r0 + i) * C + c0 + tx];
  __syncthreads();
#pragma unroll
  for (int i = ty; i < 32; i += 8)
    dst[(long)(c0 + i) * R + r0 + tx] = f2bf(tile[tx][i]);
}

// ---------------- GEMM: C[M,N] = A[M,K] * B^T (B stored [N][K]), bf16 in, fp32 acc ----------------
// 2-phase double-buffered staging (T3-minimum): issue next K-tile's global_load_lds BEFORE
// computing the current tile; single __syncthreads per tile (implicit vmcnt(0) drain lands
// after compute). XCD-swizzled block remap (nwg % 8 == 0 for both call sites).
// EPI=0: QKV epilogue (N=3072): n<2048 -> q_buf [32][2048][64] (scaled 0.125*log2e for
//        exp2-domain softmax), n<2560 -> k_buf [8][2048][64], else v^T buf [8][64][2048]
// EPI=1: fp32 C output
template <int EPI>
__global__ __launch_bounds__(256, 2) void gemm_bt(
    const ushort_t* __restrict__ A, const ushort_t* __restrict__ B,
    float* __restrict__ C,
    ushort_t* __restrict__ qb, ushort_t* __restrict__ kb, ushort_t* __restrict__ vb,
    int M, int N, int K) {
  __shared__ __attribute__((aligned(16))) ushort_t As[2][128 * 32];
  __shared__ __attribute__((aligned(16))) ushort_t Bs[2][128 * 32];
  const int t = threadIdx.x;
  const int w = t >> 6, lane = t & 63;
  const int m = lane & 15, quad = lane >> 4;
  // XCD-aware swizzle: contiguous chunk of tiles per XCD
  const int nwg = gridDim.x * gridDim.y;
  const int bid = blockIdx.y * gridDim.x + blockIdx.x;
  const int sw = (bid & 7) * (nwg >> 3) + (bid >> 3);
  const int m0 = (sw / gridDim.x) * 128, n0 = (sw % gridDim.x) * 128;
  const int wr = w >> 1, wc = w & 1;

  floatx4 acc[4][4] = {};

  auto stage = [&](int kk, int buf) {
#pragma unroll
    for (int i = 0; i < 2; ++i) {
      int c = i * 256 + t;
      int c0 = i * 256 + w * 64;
      gl_lds16(A + (long)(m0 + (c >> 2)) * K + kk + (c & 3) * 8, As[buf] + c0 * 8);
      gl_lds16(B + (long)(n0 + (c >> 2)) * K + kk + (c & 3) * 8, Bs[buf] + c0 * 8);
    }
  };

  stage(0, 0);
  __syncthreads();
  int cur = 0;
  for (int kk = 0; kk < K; kk += 32) {
    if (kk + 32 < K) stage(kk + 32, cur ^ 1);
    short8 af[4], bf[4];
#pragma unroll
    for (int i = 0; i < 4; ++i)
      af[i] = *(const short8*)(As[cur] + (wr * 64 + i * 16 + m) * 32 + quad * 8);
#pragma unroll
    for (int j = 0; j < 4; ++j)
      bf[j] = *(const short8*)(Bs[cur] + (wc * 64 + j * 16 + m) * 32 + quad * 8);
#pragma unroll
    for (int i = 0; i < 4; ++i)
#pragma unroll
      for (int j = 0; j < 4; ++j)
        acc[i][j] = __builtin_amdgcn_mfma_f32_16x16x32_bf16(af[i], bf[j], acc[i][j], 0, 0, 0);
    __syncthreads();
    cur ^= 1;
  }

#pragma unroll
  for (int i = 0; i < 4; ++i)
#pragma unroll
    for (int j = 0; j < 4; ++j)
#pragma unroll
      for (int r = 0; r < 4; ++r) {
        float v = acc[i][j][r];
        int row = m0 + wr * 64 + i * 16 + quad * 4 + r;
        int col = n0 + wc * 64 + j * 16 + m;
        if (EPI == 1) {
          C[(long)row * N + col] = v;
        } else {
          if (col < 2048) {
            // 0.125 * log2(e): softmax runs in exp2 domain
            qb[((((col >> 6) * 2048) + row) << 6) | (col & 63)] = f2bf(v * 0.18033688f);
          } else if (col < 2560) {
            int g = (col - 2048) >> 6;
            kb[(((g * 2048) + row) << 6) | (col & 63)] = f2bf(v);
          } else {
            int g = (col - 2560) >> 6;
            vb[(long)((g << 6) | (col & 63)) * 2048 + row] = f2bf(v);
          }
        }
      }
}

// ---------------- flash attention ----------------
// Q [32][S][64] bf16 (pre-scaled by 0.125*log2e), K [8][S][64] bf16, V^T [8][64][S] bf16
// -> O [S][2048] bf16
//
// Swapped QK^T: sacc = mfma(K_frag, Q_frag) so D[k][q]: each lane holds P-row slices for
// q = lane&15 -> softmax max is an in-lane tree + 2 cross-quad shuffles, P is k-contiguous
// per lane -> packed b64 LDS writes.
// l is accumulated on the MATRIX pipe: lacc = mfma(P_frag, ones, lacc) (8 extra MFMAs/iter)
// -> lands in oacc row layout, no shuffle reduce, no epilogue broadcast.
// T13 defer-max: skip O/l rescale when __all(tilemax - m <= 8) (P bounded by 2^8, bf16-safe).
// 2-phase K/V double-buffer: next tile's global_load_lds issued before QK^T; one barrier/tile.
//
// LDS swizzles (verified conflict-free at the wave64 32-bank minimum):
//   Ks/Vs: 64B rows, 16B slot ^= (row>>1)&3; applied to global SOURCE of global_load_lds
//          (dest must stay linear), and to the ds_read address.
//   Ps:    128B rows, byte ^= (row&7)<<4 on both write and read.
__global__ __launch_bounds__(256, 2) void flash_kernel(
    const ushort_t* __restrict__ Q, const ushort_t* __restrict__ Kb,
    const ushort_t* __restrict__ Vb, ushort_t* __restrict__ O, int S) {
  __shared__ __attribute__((aligned(16))) ushort_t Ks[2][128 * 64];   // 2 x 16KB [kq][krow][32]
  __shared__ __attribute__((aligned(16))) ushort_t Vs[2][128 * 64];   // 2 x 16KB [kt][d][32]
  __shared__ __attribute__((aligned(16))) ushort_t Ps[4 * 32 * 64];   // 16KB per-wave [32 q][64 k-half]
  const int t = threadIdx.x;
  const int w = t >> 6, lane = t & 63;
  const int m = lane & 15, quad = lane >> 4;
  // XCD swizzle: 64 consecutive blocks (4 heads) per XCD -> K/V stays in that XCD's L2
  const int nwg = gridDim.x * gridDim.y;
  const int bid = blockIdx.y * gridDim.x + blockIdx.x;
  const int sw = (bid & 7) * (nwg >> 3) + (bid >> 3);
  const int h = sw / gridDim.x, g = h >> 2;
  const int q0 = (sw % gridDim.x) * 128;
  const ushort_t* qp = Q + (long)h * S * 64;
  const ushort_t* kp = Kb + (long)g * S * 64;
  const ushort_t* vp = Vb + (long)g * 64 * S;

  auto stage = [&](int t0, int buf) {
#pragma unroll
    for (int i = 0; i < 4; ++i) {
      int c = i * 256 + t;
      int c0 = i * 256 + w * 64;
      int sl = ((c & 3) ^ ((c >> 3) & 3)) * 8;  // pre-swizzled global slot; LDS dest linear
      gl_lds16(kp + (long)(t0 + ((c >> 2) & 127)) * 64 + (c >> 9) * 32 + sl, Ks[buf] + c0 * 8);
      gl_lds16(vp + (long)((c >> 2) & 63) * S + t0 + (c >> 8) * 32 + sl, Vs[buf] + c0 * 8);
    }
  };

  stage(0, 0);

  short8 qf[2][2];
#pragma unroll
  for (int rt = 0; rt < 2; ++rt)
#pragma unroll
    for (int kq = 0; kq < 2; ++kq)
      qf[rt][kq] = *(const short8*)(qp + (long)(q0 + w * 32 + rt * 16 + m) * 64 + kq * 32 + quad * 8);

  short8 ones;
#pragma unroll
  for (int z = 0; z < 8; ++z) ones[z] = (short)0x3F80;  // bf16 1.0

  float mcur[2] = {-1e30f, -1e30f};
  floatx4 lacc[2] = {};
  floatx4 oacc[2][4] = {};
  char* PwB = (char*)Ps + w * 4096;
  const int swz = (m & 7) << 4;                    // Ps swizzle key (row&7 == m&7 here)
  const int kvswz = (quad ^ ((m >> 1) & 3)) * 8;   // Ks/Vs read slot (ushort units)

  __syncthreads();
  int cur = 0;
  for (int t0 = 0; t0 < S; t0 += 128) {
    if (t0 + 128 < S) stage(t0 + 128, cur ^ 1);

    // ---- QK^T (swapped: rows = k, cols = q) ----
    floatx4 sacc[2][8] = {};
    __builtin_amdgcn_s_setprio(1);
#pragma unroll
    for (int ct = 0; ct < 8; ++ct) {
      short8 kf0 = *(const short8*)(Ks[cur] + (ct * 16 + m) * 32 + kvswz);
      short8 kf1 = *(const short8*)(Ks[cur] + 4096 + (ct * 16 + m) * 32 + kvswz);
#pragma unroll
      for (int rt = 0; rt < 2; ++rt) {
        sacc[rt][ct] = __builtin_amdgcn_mfma_f32_16x16x32_bf16(kf0, qf[rt][0], sacc[rt][ct], 0, 0, 0);
        sacc[rt][ct] = __builtin_amdgcn_mfma_f32_16x16x32_bf16(kf1, qf[rt][1], sacc[rt][ct], 0, 0, 0);
      }
    }
    __builtin_amdgcn_s_setprio(0);

    // ---- online softmax, state indexed by q = m ----
    float mnew[2];
#pragma unroll
    for (int rt = 0; rt < 2; ++rt) {
      float mt[8];
#pragma unroll
      for (int ct = 0; ct < 8; ++ct)
        mt[ct] = fmaxf(fmaxf(sacc[rt][ct][0], sacc[rt][ct][1]),
                       fmaxf(sacc[rt][ct][2], sacc[rt][ct][3]));
      float mx = fmaxf(fmaxf(fmaxf(mt[0], mt[1]), fmaxf(mt[2], mt[3])),
                       fmaxf(fmaxf(mt[4], mt[5]), fmaxf(mt[6], mt[7])));
      mx = fmaxf(mx, __shfl_xor(mx, 16));
      mx = fmaxf(mx, __shfl_xor(mx, 32));
      mnew[rt] = mx;
    }

    // T13 defer-max: only rescale when some row's max grew by > 8 (exp2 domain)
    if (__all((mnew[0] - mcur[0] <= 8.f) && (mnew[1] - mcur[1] <= 8.f))) {
      mnew[0] = mcur[0];
      mnew[1] = mcur[1];
    } else {
      float al[2];
#pragma unroll
      for (int rt = 0; rt < 2; ++rt) {
        mnew[rt] = fmaxf(mcur[rt], mnew[rt]);
        al[rt] = exp2f(mcur[rt] - mnew[rt]);
        mcur[rt] = mnew[rt];
      }
      // broadcast col-state al (q=m) to row position q=quad*4+r; rescale O and l
#pragma unroll
      for (int rt = 0; rt < 2; ++rt)
#pragma unroll
        for (int r = 0; r < 4; ++r) {
          float alr = __shfl(al[rt], quad * 4 + r);
          lacc[rt][r] *= alr;
#pragma unroll
          for (int ct = 0; ct < 4; ++ct) oacc[rt][ct][r] *= alr;
        }
    }

#pragma unroll
    for (int hh = 0; hh < 2; ++hh) {
      // exp + pack + write k-half of P (rows rt*16+m, 128B rows, XOR-swizzled)
#pragma unroll
      for (int rt = 0; rt < 2; ++rt)
#pragma unroll
        for (int cl = 0; cl < 4; ++cl) {
          int ct = hh * 4 + cl;
          float p0 = exp2f(sacc[rt][ct][0] - mnew[rt]);
          float p1 = exp2f(sacc[rt][ct][1] - mnew[rt]);
          float p2 = exp2f(sacc[rt][ct][2] - mnew[rt]);
          float p3 = exp2f(sacc[rt][ct][3] - mnew[rt]);
          uint2 pk;
          pk.x = cvt_pk_bf16(p0, p1);
          pk.y = cvt_pk_bf16(p2, p3);
          *(uint2*)(PwB + ((rt * 2048 + m * 128 + cl * 32 + quad * 8) ^ swz)) = pk;
        }
      // ---- PV over this half; l-column via ones-MFMA on the matrix pipe ----
      __builtin_amdgcn_s_setprio(1);
#pragma unroll
      for (int ktl = 0; ktl < 2; ++ktl) {
        int kt = hh * 2 + ktl;
        short8 pf[2];
#pragma unroll
        for (int rt = 0; rt < 2; ++rt) {
          pf[rt] = *(const short8*)(PwB + ((rt * 2048 + m * 128 + ktl * 64 + quad * 16) ^ swz));
          lacc[rt] = __builtin_amdgcn_mfma_f32_16x16x32_bf16(pf[rt], ones, lacc[rt], 0, 0, 0);
        }
#pragma unroll
        for (int ct = 0; ct < 4; ++ct) {
          short8 vf = *(const short8*)(Vs[cur] + kt * 2048 + (ct * 16 + m) * 32 + kvswz);
#pragma unroll
          for (int rt = 0; rt < 2; ++rt)
            oacc[rt][ct] = __builtin_amdgcn_mfma_f32_16x16x32_bf16(pf[rt], vf, oacc[rt][ct], 0, 0, 0);
        }
      }
      __builtin_amdgcn_s_setprio(0);
    }

    __syncthreads();
    cur ^= 1;
  }

#pragma unroll
  for (int rt = 0; rt < 2; ++rt)
#pragma unroll
    for (int r = 0; r < 4; ++r) {
      float inv = 1.f / lacc[rt][r];   // lacc already in oacc row layout
      int srow = q0 + w * 32 + rt * 16 + quad * 4 + r;
#pragma unroll
      for (int ct = 0; ct < 4; ++ct)
        O[(long)srow * 2048 + h * 64 + ct * 16 + m] = f2bf(oacc[rt][ct][r] * inv);
    }
}

// ---------------- launch ----------------

extern "C" void kernel_launch(void* const* d_in, const int* in_sizes, int n_in,
                              void* d_out, int out_size, void* d_ws, size_t ws_size,
                              hipStream_t stream) {
  (void)in_sizes; (void)n_in; (void)out_size; (void)ws_size;
  const float* x  = (const float*)d_in[0];
  const float* wq = (const float*)d_in[1];
  const float* wk = (const float*)d_in[2];
  const float* wv = (const float*)d_in[3];
  const float* wo = (const float*)d_in[4];
  float* out = (float*)d_out;
  char* ws = (char*)d_ws;
  const size_t MB = 1u << 20;

  ushort_t* xb    = (ushort_t*)(ws);            // 8 MB  x bf16 [2048][2048]
  ushort_t* wqkvT = (ushort_t*)(ws + 8 * MB);   // 12 MB [3072][2048]
  ushort_t* woT   = (ushort_t*)(ws + 20 * MB);  // 8 MB  [2048][2048]
  ushort_t* qbuf  = (ushort_t*)(ws + 28 * MB);  // 8 MB  [32][2048][64]
  ushort_t* kbuf  = (ushort_t*)(ws + 36 * MB);  // 2 MB  [8][2048][64]
  ushort_t* vbuf  = (ushort_t*)(ws + 38 * MB);  // 2 MB  [8][64][2048]
  ushort_t* attn  = xb;                         // alias: xb dead after gemm<0>

  conv_x_kernel<<<4096, 256, 0, stream>>>(x, xb, 2048 * 2048 / 4);
  dim3 tb(32, 8);
  transpose_conv<<<dim3(64, 64), tb, 0, stream>>>(wq, wqkvT, 2048, 2048);
  transpose_conv<<<dim3(16, 64), tb, 0, stream>>>(wk, wqkvT + 2048 * 2048, 2048, 512);
  transpose_conv<<<dim3(16, 64), tb, 0, stream>>>(wv, wqkvT + 2560 * 2048, 2048, 512);
  transpose_conv<<<dim3(64, 64), tb, 0, stream>>>(wo, woT, 2048, 2048);

  gemm_bt<0><<<dim3(24, 16), 256, 0, stream>>>(xb, wqkvT, nullptr, qbuf, kbuf, vbuf,
                                               2048, 3072, 2048);
  flash_kernel<<<dim3(16, 32), 256, 0, stream>>>(qbuf, kbuf, vbuf, attn, 2048);
  gemm_bt<1><<<dim3(16, 16), 256, 0, stream>>>(attn, woT, out, nullptr, nullptr, nullptr,
                                               2048, 2048, 2048);
}